// Round 1
// baseline (466.772 us; speedup 1.0000x reference)
//
#include <hip/hip_runtime.h>

// Q = L L^T for packed lower-triangular 3x3 Cholesky factors.
// packed order: a=(0,0) b=(1,0) c=(1,1) d=(2,0) e=(2,1) f=(2,2)
// Each thread handles TWO batches:
//   in:  12 floats at elem 12*t (byte 48*t, 16-aligned)  -> 3x float4 loads
//   out: 18 floats at elem 18*t (byte 72*t,  8-aligned)  -> 9x float2 stores

__global__ __launch_bounds__(256) void getcov_kernel(
    const float* __restrict__ in, float* __restrict__ out, int npairs) {
    int t = blockIdx.x * blockDim.x + threadIdx.x;
    if (t >= npairs) return;

    const float4* __restrict__ in4 = reinterpret_cast<const float4*>(in + (size_t)t * 12);
    float4 v0 = in4[0];
    float4 v1 = in4[1];
    float4 v2 = in4[2];

    // batch 0
    float a0 = v0.x, b0 = v0.y, c0 = v0.z, d0 = v0.w, e0 = v1.x, f0 = v1.y;
    // batch 1
    float a1 = v1.z, b1 = v1.w, c1 = v2.x, d1 = v2.y, e1 = v2.z, f1 = v2.w;

    float q0_00 = a0 * a0;
    float q0_01 = a0 * b0;
    float q0_02 = a0 * d0;
    float q0_11 = b0 * b0 + c0 * c0;
    float q0_12 = b0 * d0 + c0 * e0;
    float q0_22 = d0 * d0 + e0 * e0 + f0 * f0;

    float q1_00 = a1 * a1;
    float q1_01 = a1 * b1;
    float q1_02 = a1 * d1;
    float q1_11 = b1 * b1 + c1 * c1;
    float q1_12 = b1 * d1 + c1 * e1;
    float q1_22 = d1 * d1 + e1 * e1 + f1 * f1;

    float2* __restrict__ o2 = reinterpret_cast<float2*>(out + (size_t)t * 18);
    // batch 0: [q00 q01 q02 | q01 q11 q12 | q02 q12 q22]
    o2[0] = make_float2(q0_00, q0_01);
    o2[1] = make_float2(q0_02, q0_01);
    o2[2] = make_float2(q0_11, q0_12);
    o2[3] = make_float2(q0_02, q0_12);
    // straddle: q0_22 then batch1 q00
    o2[4] = make_float2(q0_22, q1_00);
    o2[5] = make_float2(q1_01, q1_02);
    o2[6] = make_float2(q1_01, q1_11);
    o2[7] = make_float2(q1_12, q1_02);
    o2[8] = make_float2(q1_12, q1_22);
}

extern "C" void kernel_launch(void* const* d_in, const int* in_sizes, int n_in,
                              void* d_out, int out_size, void* d_ws, size_t ws_size,
                              hipStream_t stream) {
    const float* in = (const float*)d_in[0];
    float* out = (float*)d_out;
    int n = in_sizes[0] / 6;      // number of batches (8388608)
    int npairs = n / 2;           // n is even for this problem
    int block = 256;
    int grid = (npairs + block - 1) / block;
    getcov_kernel<<<grid, block, 0, stream>>>(in, out, npairs);
}

// Round 2
// 422.917 us; speedup vs baseline: 1.1037x; 1.1037x over previous
//
#include <hip/hip_runtime.h>

// Q = L L^T for packed lower-triangular 3x3 Cholesky factors.
// packed order: a=(0,0) b=(1,0) c=(1,1) d=(2,0) e=(2,1) f=(2,2)
//
// LDS-staged version for perfect global coalescing:
//   stage in (24 KB, float4, lane-contiguous) -> compute in regs ->
//   scatter to LDS in output order (stride 9, conflict-free) ->
//   store out (36 KB, float4, lane-contiguous).
// 36 KB LDS -> 4 blocks/CU (16 waves/CU).

constexpr int B = 1024;  // batches per block (8388608 % 1024 == 0)
constexpr int T = 256;   // threads per block

__global__ __launch_bounds__(T) void getcov_kernel(
    const float* __restrict__ in, float* __restrict__ out) {
  __shared__ float4 lds4[(9 * B) / 4];  // 36 KB; input phase uses first 24 KB
  float* lds = reinterpret_cast<float*>(lds4);

  const int tid = threadIdx.x;
  const size_t base_b = (size_t)blockIdx.x * B;

  // ---- stage: global -> LDS, fully coalesced float4 ----
  const float4* __restrict__ gin =
      reinterpret_cast<const float4*>(in) + (base_b * 6) / 4;
#pragma unroll
  for (int j = 0; j < 6; ++j) {
    lds4[tid + T * j] = gin[tid + T * j];
  }
  __syncthreads();

  // ---- compute: 4 batches/thread, results held in registers ----
  // lane stride 6 words -> 2-way bank aliasing (free on wave64/32-bank)
  float q[4][6];
#pragma unroll
  for (int j = 0; j < 4; ++j) {
    const int b = tid + T * j;
    const float* p = &lds[6 * b];
    const float a = p[0], bb = p[1], c = p[2], d = p[3], e = p[4], f = p[5];
    q[j][0] = a * a;                       // Q00
    q[j][1] = a * bb;                      // Q01 = Q10
    q[j][2] = a * d;                       // Q02 = Q20
    q[j][3] = bb * bb + c * c;             // Q11
    q[j][4] = bb * d + c * e;              // Q12 = Q21
    q[j][5] = d * d + e * e + f * f;       // Q22
  }
  __syncthreads();  // all LDS reads done before overwriting buffer

  // ---- scatter results into LDS in output order ----
  // lane stride 9 words, gcd(9,32)=1 -> conflict-free
#pragma unroll
  for (int j = 0; j < 4; ++j) {
    const int b = tid + T * j;
    float* o = &lds[9 * b];
    o[0] = q[j][0]; o[1] = q[j][1]; o[2] = q[j][2];
    o[3] = q[j][1]; o[4] = q[j][3]; o[5] = q[j][4];
    o[6] = q[j][2]; o[7] = q[j][4]; o[8] = q[j][5];
  }
  __syncthreads();

  // ---- store: LDS -> global, fully coalesced float4 ----
  float4* __restrict__ gout =
      reinterpret_cast<float4*>(out) + (base_b * 9) / 4;
#pragma unroll
  for (int j = 0; j < 9; ++j) {
    gout[tid + T * j] = lds4[tid + T * j];
  }
}

extern "C" void kernel_launch(void* const* d_in, const int* in_sizes, int n_in,
                              void* d_out, int out_size, void* d_ws, size_t ws_size,
                              hipStream_t stream) {
  const float* in = (const float*)d_in[0];
  float* out = (float*)d_out;
  const int nbatch = in_sizes[0] / 6;  // 8388608
  const int grid = nbatch / B;         // exact: 8192 blocks
  getcov_kernel<<<grid, T, 0, stream>>>(in, out);
}